// Round 1
// baseline (159.890 us; speedup 1.0000x reference)
//
#include <hip/hip_runtime.h>
#include <hip/hip_fp16.h>
#include <cstdint>

typedef _Float16 f16x8 __attribute__((ext_vector_type(8)));
typedef _Float16 f16x4 __attribute__((ext_vector_type(4)));
typedef float    f32x4 __attribute__((ext_vector_type(4)));
typedef float    f32x16 __attribute__((ext_vector_type(16)));

__device__ __forceinline__ f32x4 mfma16(f16x8 a, f16x8 b, f32x4 c) {
  return __builtin_amdgcn_mfma_f32_16x16x32_f16(a, b, c, 0, 0, 0);
}
__device__ __forceinline__ f32x16 mfma32(f16x8 a, f16x8 b, f32x16 c) {
  return __builtin_amdgcn_mfma_f32_32x32x16_f16(a, b, c, 0, 0, 0);
}
__device__ __forceinline__ void gload_lds16(const void* g, void* l) {
  __builtin_amdgcn_global_load_lds(
      (const __attribute__((address_space(1))) void*)g,
      (__attribute__((address_space(3))) void*)l, 16, 0, 0);
}
__device__ __forceinline__ unsigned pkrtz(float a, float b) {
  auto h2 = __builtin_amdgcn_cvt_pkrtz(a, b);
  return __builtin_bit_cast(unsigned, h2);
}

// transpose one 32x32 tile with 256 threads
__device__ __forceinline__ void wtrans_tile256(
    const float* __restrict__ S, _Float16* __restrict__ D,
    int R, int C, int bx, int by, float sc, float* tle /* [32*33] */)
{
  int tx = threadIdx.x & 31, ty = threadIdx.x >> 5;
  int x = bx * 32 + tx;
#pragma unroll
  for (int j = 0; j < 4; ++j) {
    int y = by * 32 + ty + j * 8;
    tle[(ty + j * 8) * 33 + tx] = S[(size_t)y * C + x];
  }
  __syncthreads();
  int xo = by * 32 + tx;
#pragma unroll
  for (int j = 0; j < 4; ++j) {
    int yo = bx * 32 + ty + j * 8;
    D[(size_t)yo * R + xo] = (_Float16)(tle[tx * 33 + ty + j * 8] * sc);
  }
}

// ---------- prep: DyT(xq,xk)->f16 + Wq/Wkv transposes (WqT pre-scaled) ----------
__global__ __launch_bounds__(256) void prep_kernel(
    const float* __restrict__ Xq, const float* __restrict__ Xk,
    const float* __restrict__ aq, const float* __restrict__ gq,
    const float* __restrict__ ak, const float* __restrict__ gk,
    _Float16* __restrict__ Yq, _Float16* __restrict__ Yk,
    const float* __restrict__ Wq, const float* __restrict__ Wkv,
    _Float16* __restrict__ WqT, _Float16* __restrict__ WkvT)
{
  if (blockIdx.x < 8192) {
    int i = blockIdx.x * 256 + threadIdx.x;
    const float* X; const float* gamma; float a; _Float16* Y;
    if (i < 1048576) { X = Xq; gamma = gq; a = aq[0]; Y = Yq; }
    else { i -= 1048576; X = Xk; gamma = gk; a = ak[0]; Y = Yk; }
    float4 v = ((const float4*)X)[i];
    int c = (i * 4) & 1023;
    f16x4 o;
    o[0] = (_Float16)(gamma[c + 0] * tanhf(a * v.x));
    o[1] = (_Float16)(gamma[c + 1] * tanhf(a * v.y));
    o[2] = (_Float16)(gamma[c + 2] * tanhf(a * v.z));
    o[3] = (_Float16)(gamma[c + 3] * tanhf(a * v.w));
    *(f16x4*)(Y + (size_t)i * 4) = o;
  } else {
    __shared__ float tle[32 * 33];
    int t = blockIdx.x - 8192;
    const float* S; _Float16* D; int R, C; float sc = 1.0f;
    if (t < 1024)      { S = Wq;  D = WqT;  R = 1024; C = 1024; sc = 0.18033688011112042f; }
    else               { S = Wkv; D = WkvT; R = 1024; C = 2048; t -= 1024; }
    const int tilesX = C >> 5;
    wtrans_tile256(S, D, R, C, t % tilesX, t / tilesX, sc, tle);
  }
}

// ---- GEMM 128x128 tile, BK=32, 512 threads (8 waves, 4x2), 3-buf counted vmcnt --
template <int EPI>
__device__ __forceinline__ void gemm_body(
    _Float16* smem,                     // 3 bufs x (A 4096 + B 4096) f16 = 48 KB
    const _Float16* __restrict__ A, const _Float16* __restrict__ BT,
    int N, int K, int bm, int bn,
    _Float16* __restrict__ C16, _Float16* __restrict__ X16,
    const float* __restrict__ bias, const float* __restrict__ alpha_p,
    const float* __restrict__ gamma, const _Float16* __restrict__ resid16,
    float* __restrict__ outf)
{
  const int tid = threadIdx.x;                   // 0..511
  const int w = tid >> 6, l = tid & 63;
  const int g = l >> 4, r = l & 15;
  const int wm = w >> 1, wn = w & 1;             // 4 x 2 wave grid
  const int srow = tid >> 2;                     // 0..127
  const int skey = (tid >> 3) & 3;               // = (srow>>1)&3
  const int scol = ((tid & 3) ^ skey) << 3;      // pre-swizzled source f16 col

  const _Float16* gA = A + (size_t)(bm + srow) * K + scol;
  const _Float16* gB = BT + (size_t)(bn + srow) * K + scol;
  char* dA = (char*)smem + tid * 16;             // A region [0,8192) per buf
  char* dB = (char*)smem + 8192 + tid * 16;      // B region [8192,16384) per buf

  const int rk = (r >> 1) & 3;                   // read-side swizzle key
  const int gsw = (g ^ rk) << 3;                 // swizzled fragment col (f16)

  f32x4 acc[2][4] = {};
  const int KT = K >> 5;

  auto stage = [&](int buf) {
    gload_lds16(gA, dA + buf * 16384);
    gload_lds16(gB, dB + buf * 16384);
    gA += 32; gB += 32;
  };

  stage(0);
  stage(1);

  int cur = 0;
  for (int kt = 0; kt < KT; ++kt) {
    if (kt < KT - 1) asm volatile("s_waitcnt vmcnt(2) lgkmcnt(0)" ::: "memory");
    else             asm volatile("s_waitcnt vmcnt(0) lgkmcnt(0)" ::: "memory");
    __builtin_amdgcn_s_barrier();
    asm volatile("" ::: "memory");
    if (kt + 2 < KT) { int b2 = cur + 2; if (b2 >= 3) b2 -= 3; stage(b2); }
    const _Float16* Asc = smem + cur * 8192;
    const _Float16* Bsc = Asc + 4096;
    f16x8 af[2], bf[4];
#pragma unroll
    for (int m = 0; m < 2; ++m)
      af[m] = *(const f16x8*)(Asc + (wm * 32 + m * 16 + r) * 32 + gsw);
#pragma unroll
    for (int n = 0; n < 4; ++n)
      bf[n] = *(const f16x8*)(Bsc + (wn * 64 + n * 16 + r) * 32 + gsw);
    __builtin_amdgcn_s_setprio(1);
#pragma unroll
    for (int m = 0; m < 2; ++m)
#pragma unroll
      for (int n = 0; n < 4; ++n)
        acc[m][n] = mfma16(af[m], bf[n], acc[m][n]);
    __builtin_amdgcn_s_setprio(0);
    ++cur; if (cur == 3) cur = 0;
  }

  const int row0 = bm + wm * 32 + 4 * g;
  const int col0 = bn + wn * 64 + r;

  if constexpr (EPI == 5) {
    if (bn < 1024) {
#pragma unroll
      for (int m = 0; m < 2; ++m)
#pragma unroll
        for (int n = 0; n < 4; ++n)
#pragma unroll
          for (int rr = 0; rr < 4; ++rr)
            C16[(size_t)(row0 + m * 16 + rr) * 1024 + col0 + n * 16] =
                (_Float16)acc[m][n][rr];
    } else {
#pragma unroll
      for (int m = 0; m < 2; ++m) {
        const int row = row0 + m * 16;
        const int bq = row >> 10, nk = row & 1023;
#pragma unroll
        for (int n = 0; n < 4; ++n) {
          const int vcol = col0 + n * 16 - 1024;
          f16x4 t;
#pragma unroll
          for (int rr = 0; rr < 4; ++rr) t[rr] = (_Float16)acc[m][n][rr];
          *(f16x4*)(X16 + ((size_t)((bq << 4) + (vcol >> 6)) * 64 + (vcol & 63)) * 1024 + nk) = t;
        }
      }
    }
    return;
  }

#pragma unroll
  for (int m = 0; m < 2; ++m) {
#pragma unroll
    for (int n = 0; n < 4; ++n) {
#pragma unroll
      for (int rr = 0; rr < 4; ++rr) {
        const int row = row0 + m * 16 + rr;
        const int col = col0 + n * 16;
        const size_t idx = (size_t)row * N + col;
        float v = acc[m][n][rr];
        if constexpr (EPI == 0) {
          C16[idx] = (_Float16)v;
        } else if constexpr (EPI == 2) {
          float x = v + bias[col];
          X16[idx] = (_Float16)x;
          C16[idx] = (_Float16)(gamma[col] * tanhf(alpha_p[0] * x));
        } else if constexpr (EPI == 3) {
          float tt = v + bias[col];
          C16[idx] = (_Float16)(0.5f * tt * (1.0f + erff(tt * 0.7071067811865475f)));
        } else {
          outf[idx] = (float)resid16[idx] + v + bias[col];
        }
      }
    }
  }
}

template <int EPI>
__global__ __launch_bounds__(512, 6) void gemm_f16(
    const _Float16* __restrict__ A, const _Float16* __restrict__ BT,
    int N, int K, int nTnShift,
    _Float16* __restrict__ C16, _Float16* __restrict__ X16,
    const float* __restrict__ bias, const float* __restrict__ alpha_p,
    const float* __restrict__ gamma, const _Float16* __restrict__ resid16,
    float* __restrict__ outf)
{
  __shared__ __align__(16) _Float16 smem[24576];
  const int chunk = gridDim.x >> 3;
  const int bid = ((int)blockIdx.x & 7) * chunk + ((int)blockIdx.x >> 3);
  const int bm = (bid >> nTnShift) << 7;
  const int bn = (bid & ((1 << nTnShift) - 1)) << 7;
  gemm_body<EPI>(smem, A, BT, N, K, bm, bn,
                 C16, X16, bias, alpha_p, gamma, resid16, outf);
}

// fused Q-proj + KV-proj (K + transposed-V epilogue), one dispatch, XCD-swizzled
__global__ __launch_bounds__(512, 6) void gemm_qkv(
    const _Float16* __restrict__ Aq, const _Float16* __restrict__ Bq,
    _Float16* __restrict__ Cq,
    const _Float16* __restrict__ Ak, const _Float16* __restrict__ Bk,
    _Float16* __restrict__ K16, _Float16* __restrict__ VT)
{
  __shared__ __align__(16) _Float16 smem[24576];
  int bid = ((int)blockIdx.x & 7) * 96 + ((int)blockIdx.x >> 3);
  if (bid < 256) {
    gemm_body<0>(smem, Aq, Bq, 1024, 1024, (bid >> 3) << 7, (bid & 7) << 7,
                 Cq, nullptr, nullptr, nullptr, nullptr, nullptr, nullptr);
  } else {
    bid -= 256;
    gemm_body<5>(smem, Ak, Bk, 2048, 1024, (bid >> 4) << 7, (bid & 15) << 7,
                 K16, VT, nullptr, nullptr, nullptr, nullptr, nullptr);
  }
}

// ------- Flash attention (blocks 0..511) + Wproj/W1/W2 transposes (512..5631) ---
// 256-thread blocks (4 waves x 32 q-rows = 128 q-rows), shared K/V tiles.
// 4-buf LDS ring (64 KB), stage 2 tiles ahead, counted vmcnt(8), ONE barrier/iter.
// Safety: write@iter k goes to buf (k+2)&3 = buffer last read at iter k-2; the
// per-iter barrier chain separates them (reads of buf X at iter k-2 complete
// before any wave passes barrier of iter k-1; the write is issued after it).
__global__ __launch_bounds__(256) void attn_kernel(
    const _Float16* __restrict__ Q, const _Float16* __restrict__ K16,
    const _Float16* __restrict__ VT, _Float16* __restrict__ O,
    const float* __restrict__ Wproj, const float* __restrict__ W1,
    const float* __restrict__ W2,
    _Float16* __restrict__ WprojT, _Float16* __restrict__ W1T,
    _Float16* __restrict__ W2T)
{
  __shared__ __align__(16) char smemc[65536];   // 4 bufs x (K 8KB | V 8KB)

  const int tid = threadIdx.x;

  if (blockIdx.x >= 512) {
    // 256-thread 32x32 transpose tiles
    int t = blockIdx.x - 512;
    const float* S; _Float16* D; int R, C;
    if (t < 1024)      { S = Wproj; D = WprojT; R = 1024; C = 1024; }
    else if (t < 3072) { S = W1;    D = W1T;    R = 1024; C = 2048; t -= 1024; }
    else               { S = W2;    D = W2T;    R = 2048; C = 1024; t -= 3072; }
    const int tilesX = C >> 5;
    wtrans_tile256(S, D, R, C, t % tilesX, t / tilesX, 1.0f, (float*)smemc);
    return;
  }

  const int bid = ((int)blockIdx.x & 7) * 64 + ((int)blockIdx.x >> 3);
  const int qb = bid & 7, hh = (bid >> 3) & 15, b = bid >> 7;
  const int w = tid >> 6, l = tid & 63;
  const int r = l & 31, h2 = l >> 5;
  const int q0 = qb * 128 + w * 32;

  f16x8 qf[4];
  {
    const _Float16* qp = Q + (size_t)(b * 1024 + q0 + r) * 1024 + hh * 64 + 8 * h2;
#pragma unroll
    for (int s = 0; s < 4; ++s) qf[s] = *(const f16x8*)(qp + s * 16);
  }

  f32x16 oacc0 = {}, oacc1 = {};
  float rl0 = 0.f, rl1 = 0.f, rl2 = 0.f, rl3 = 0.f;

  const int srow = tid >> 3, sslot = tid & 7;    // srow 0..31
  const int swz = (sslot ^ (srow & 7)) << 3;     // (row+32j)&7 == row&7
  const _Float16* kbase = K16 + (size_t)(b * 1024 + srow) * 1024 + hh * 64 + swz;
  const _Float16* vbase = VT + ((size_t)((b * 16 + hh) * 64) + srow) * 1024 + swz;
  char* kd0 = (char*)smemc + tid * 16;           // K region [0,8192) per buf
  char* vd0 = (char*)smemc + 8192 + tid * 16;    // V region [8192,16384) per buf

  auto stage = [&](int t) {
    const size_t kb = (size_t)(t << 6);
    const int buf = t & 3;
    char* kd = kd0 + buf * 16384;
    char* vd = vd0 + buf * 16384;
#pragma unroll
    for (int j = 0; j < 2; ++j)
      gload_lds16(kbase + (kb + 32 * j) * 1024, kd + j * 4096);
#pragma unroll
    for (int j = 0; j < 2; ++j)
      gload_lds16(vbase + (size_t)(32 * j) * 1024 + kb, vd + j * 4096);
  };

  stage(0);
  stage(1);

  const int rsw0 = r & 7;

  for (int kt = 0; kt < 16; ++kt) {
    if (kt + 2 < 16) stage(kt + 2);              // issued BEFORE the wait
    if (kt < 14)       asm volatile("s_waitcnt vmcnt(8)" ::: "memory");
    else if (kt == 14) asm volatile("s_waitcnt vmcnt(4)" ::: "memory");
    else               asm volatile("s_waitcnt vmcnt(0)" ::: "memory");
    __builtin_amdgcn_s_barrier();
    asm volatile("" ::: "memory");

    const _Float16* Kc = (const _Float16*)(smemc + (kt & 3) * 16384);
    const _Float16* Vc = Kc + 4096;

    f32x16 s0 = {}, s1 = {};
    __builtin_amdgcn_s_setprio(1);
#pragma unroll
    for (int s = 0; s < 4; ++s) {
      const int cch = 2 * s + h2;
      f16x8 a0 = *(const f16x8*)(Kc + r * 64 + ((cch ^ rsw0) << 3));
      f16x8 a1 = *(const f16x8*)(Kc + (32 + r) * 64 + ((cch ^ rsw0) << 3));
      s0 = mfma32(a0, qf[s], s0);
      s1 = mfma32(a1, qf[s], s1);
    }
    __builtin_amdgcn_s_setprio(0);

    // p = 2^s; 4 partial l-accumulators (short dep chains), one shfl at end
#pragma unroll
    for (int i = 0; i < 16; i += 4) {
      s0[i]   = __builtin_amdgcn_exp2f(s0[i]);   rl0 += s0[i];
      s0[i+1] = __builtin_amdgcn_exp2f(s0[i+1]); rl1 += s0[i+1];
      s0[i+2] = __builtin_amdgcn_exp2f(s0[i+2]); rl2 += s0[i+2];
      s0[i+3] = __builtin_amdgcn_exp2f(s0[i+3]); rl3 += s0[i+3];
    }
#pragma unroll
    for (int i = 0; i < 16; i += 4) {
      s1[i]   = __builtin_amdgcn_exp2f(s1[i]);   rl0 += s1[i];
      s1[i+1] = __builtin_amdgcn_exp2f(s1[i+1]); rl1 += s1[i+1];
      s1[i+2] = __builtin_amdgcn_exp2f(s1[i+2]); rl2 += s1[i+2];
      s1[i+3] = __builtin_amdgcn_exp2f(s1[i+3]); rl3 += s1[i+3];
    }

    unsigned own[16];
#pragma unroll
    for (int u = 0; u < 8; ++u) {
      const int tb = (u & 3) * 4;
      if (u < 4) {
        own[2 * u]     = pkrtz(s0[tb], s0[tb + 1]);
        own[2 * u + 1] = pkrtz(s0[tb + 2], s0[tb + 3]);
      } else {
        own[2 * u]     = pkrtz(s1[tb], s1[tb + 1]);
        own[2 * u + 1] = pkrtz(s1[tb + 2], s1[tb + 3]);
      }
    }
    f16x8 pf[4];
#pragma unroll
    for (int s = 0; s < 4; ++s) {
      auto r0 = __builtin_amdgcn_permlane32_swap(own[4 * s], own[4 * s + 2], false, false);
      auto r1 = __builtin_amdgcn_permlane32_swap(own[4 * s + 1], own[4 * s + 3], false, false);
      union { unsigned u[4]; f16x8 v; } fu;
      fu.u[0] = r0[0]; fu.u[1] = r1[0]; fu.u[2] = r0[1]; fu.u[3] = r1[1];
      pf[s] = fu.v;
    }

    __builtin_amdgcn_s_setprio(1);
#pragma unroll
    for (int s = 0; s < 4; ++s) {
      const int cch = 2 * s + h2;
      f16x8 va = *(const f16x8*)(Vc + r * 64 + ((cch ^ rsw0) << 3));
      f16x8 vb = *(const f16x8*)(Vc + (32 + r) * 64 + ((cch ^ rsw0) << 3));
      oacc0 = mfma32(va, pf[s], oacc0);
      oacc1 = mfma32(vb, pf[s], oacc1);
    }
    __builtin_amdgcn_s_setprio(0);
    asm volatile("" ::: "memory");   // keep next iter's stage below this point
  }

  float run_l = (rl0 + rl1) + (rl2 + rl3);
  const float inv = 1.0f / (run_l + __shfl_xor(run_l, 32));
  _Float16* op = O + (size_t)(b * 1024 + q0 + r) * 1024 + hh * 64 + 4 * h2;
#pragma unroll
  for (int u = 0; u < 4; ++u) {
    f16x4 t0, t1;
#pragma unroll
    for (int v = 0; v < 4; ++v) {
      t0[v] = (_Float16)(oacc0[4 * u + v] * inv);
      t1[v] = (_Float16)(oacc1[4 * u + v] * inv);
    }
    *(f16x4*)(op + 8 * u) = t0;
    *(f16x4*)(op + 32 + 8 * u) = t1;
  }
}

extern "C" void kernel_launch(void* const* d_in, const int* in_sizes, int n_in,
                              void* d_out, int out_size, void* d_ws, size_t ws_size,
                              hipStream_t stream)
{
  const float* xk      = (const float*)d_in[0];
  const float* xq      = (const float*)d_in[1];
  const float* alpha_q = (const float*)d_in[2];
  const float* gamma_q = (const float*)d_in[3];
  const float* alpha_k = (const float*)d_in[4];
  const float* gamma_k = (const float*)d_in[5];
  const float* Wq      = (const float*)d_in[6];
  const float* Wkv     = (const float*)d_in[7];
  const float* Wproj   = (const float*)d_in[8];
  const float* bproj   = (const float*)d_in[9];
  const float* alpha2  = (const float*)d_in[10];
  const float* gamma2  = (const float*)d_in[11];
  const float* W1      = (const float*)d_in[12];
  const float* b1      = (const float*)d_in[13];
  const float* W2      = (const float*)d_in[14];
  const float* b2      = (const float*)d_in[15];

  char* p = (char*)d_ws;
  _Float16* xqn    = (_Float16*)p; p += 8388608;
  _Float16* xkn    = (_Float16*)p; p += 8388608;
  _Float16* WqT    = (_Float16*)p; p += 2097152;
  _Float16* WkvT   = (_Float16*)p; p += 4194304;
  _Float16* WprojT = (_Float16*)p; p += 2097152;
  _Float16* W1T    = (_Float16*)p; p += 4194304;
  _Float16* W2T    = (_Float16*)p; p += 4194304;
  _Float16* q16    = (_Float16*)p; p += 8388608;
  _Float16* vt16   = (_Float16*)p; p += 8388608;
  _Float16* k16    = (_Float16*)p; p += 8388608;
  _Float16* h16    = (_Float16*)p; p += 16777216;
  _Float16* o16    = (_Float16*)p; p += 8388608;
  // aliases (lifetimes disjoint):
  _Float16* x16  = q16;           // q16 dead after attn; x written at proj
  _Float16* g16  = xqn;           // xqn dead after gemm_qkv
  float*    outf = (float*)d_out;

  prep_kernel<<<11264, 256, 0, stream>>>(xq, xk, alpha_q, gamma_q, alpha_k, gamma_k,
      xqn, xkn, Wq, Wkv, WqT, WkvT);
  gemm_qkv<<<768, 512, 0, stream>>>(xqn, WqT, q16, xkn, WkvT, k16, vt16);
  attn_kernel<<<5632, 256, 0, stream>>>(q16, k16, vt16, o16,
      Wproj, W1, W2, WprojT, W1T, W2T);
  gemm_f16<2><<<256, 512, 0, stream>>>(o16, WprojT, 1024, 1024, 3,
      g16, x16, bproj, alpha2, gamma2, nullptr, nullptr);
  gemm_f16<3><<<512, 512, 0, stream>>>(g16, W1T, 2048, 1024, 4,
      h16, nullptr, b1, nullptr, nullptr, nullptr, nullptr);
  gemm_f16<4><<<256, 512, 0, stream>>>(h16, W2T, 1024, 2048, 3,
      nullptr, nullptr, b2, nullptr, nullptr, x16, outf);
}

// Round 2
// 159.796 us; speedup vs baseline: 1.0006x; 1.0006x over previous
//
#include <hip/hip_runtime.h>
#include <hip/hip_fp16.h>
#include <cstdint>

typedef _Float16 f16x8 __attribute__((ext_vector_type(8)));
typedef _Float16 f16x4 __attribute__((ext_vector_type(4)));
typedef float    f32x4 __attribute__((ext_vector_type(4)));
typedef float    f32x16 __attribute__((ext_vector_type(16)));

__device__ __forceinline__ f32x4 mfma16(f16x8 a, f16x8 b, f32x4 c) {
  return __builtin_amdgcn_mfma_f32_16x16x32_f16(a, b, c, 0, 0, 0);
}
__device__ __forceinline__ f32x16 mfma32(f16x8 a, f16x8 b, f32x16 c) {
  return __builtin_amdgcn_mfma_f32_32x32x16_f16(a, b, c, 0, 0, 0);
}
__device__ __forceinline__ void gload_lds16(const void* g, void* l) {
  __builtin_amdgcn_global_load_lds(
      (const __attribute__((address_space(1))) void*)g,
      (__attribute__((address_space(3))) void*)l, 16, 0, 0);
}
__device__ __forceinline__ unsigned pkrtz(float a, float b) {
  auto h2 = __builtin_amdgcn_cvt_pkrtz(a, b);
  return __builtin_bit_cast(unsigned, h2);
}

// transpose one 32x32 tile with 256 threads
__device__ __forceinline__ void wtrans_tile256(
    const float* __restrict__ S, _Float16* __restrict__ D,
    int R, int C, int bx, int by, float sc, float* tle /* [32*33] */)
{
  int tx = threadIdx.x & 31, ty = threadIdx.x >> 5;
  int x = bx * 32 + tx;
#pragma unroll
  for (int j = 0; j < 4; ++j) {
    int y = by * 32 + ty + j * 8;
    tle[(ty + j * 8) * 33 + tx] = S[(size_t)y * C + x];
  }
  __syncthreads();
  int xo = by * 32 + tx;
#pragma unroll
  for (int j = 0; j < 4; ++j) {
    int yo = bx * 32 + ty + j * 8;
    D[(size_t)yo * R + xo] = (_Float16)(tle[tx * 33 + ty + j * 8] * sc);
  }
}

// ---------- prep: DyT(xq,xk)->f16 + ALL weight transposes (WqT pre-scaled) ------
// blocks 0..8191: elementwise DyT; 8192..16383: 32x32 transpose tiles for
// Wq(1024) Wkv(2048) Wproj(1024) W1(2048) W2(2048).
__global__ __launch_bounds__(256) void prep_kernel(
    const float* __restrict__ Xq, const float* __restrict__ Xk,
    const float* __restrict__ aq, const float* __restrict__ gq,
    const float* __restrict__ ak, const float* __restrict__ gk,
    _Float16* __restrict__ Yq, _Float16* __restrict__ Yk,
    const float* __restrict__ Wq, const float* __restrict__ Wkv,
    _Float16* __restrict__ WqT, _Float16* __restrict__ WkvT,
    const float* __restrict__ Wproj, const float* __restrict__ W1,
    const float* __restrict__ W2,
    _Float16* __restrict__ WprojT, _Float16* __restrict__ W1T,
    _Float16* __restrict__ W2T)
{
  if (blockIdx.x < 8192) {
    int i = blockIdx.x * 256 + threadIdx.x;
    const float* X; const float* gamma; float a; _Float16* Y;
    if (i < 1048576) { X = Xq; gamma = gq; a = aq[0]; Y = Yq; }
    else { i -= 1048576; X = Xk; gamma = gk; a = ak[0]; Y = Yk; }
    float4 v = ((const float4*)X)[i];
    int c = (i * 4) & 1023;
    f16x4 o;
    o[0] = (_Float16)(gamma[c + 0] * tanhf(a * v.x));
    o[1] = (_Float16)(gamma[c + 1] * tanhf(a * v.y));
    o[2] = (_Float16)(gamma[c + 2] * tanhf(a * v.z));
    o[3] = (_Float16)(gamma[c + 3] * tanhf(a * v.w));
    *(f16x4*)(Y + (size_t)i * 4) = o;
  } else {
    __shared__ float tle[32 * 33];
    int t = blockIdx.x - 8192;
    const float* S; _Float16* D; int R, C; float sc = 1.0f;
    if (t < 1024)      { S = Wq;    D = WqT;    R = 1024; C = 1024; sc = 0.18033688011112042f; }
    else if (t < 3072) { S = Wkv;   D = WkvT;   R = 1024; C = 2048; t -= 1024; }
    else if (t < 4096) { S = Wproj; D = WprojT; R = 1024; C = 1024; t -= 3072; }
    else if (t < 6144) { S = W1;    D = W1T;    R = 1024; C = 2048; t -= 4096; }
    else               { S = W2;    D = W2T;    R = 2048; C = 1024; t -= 6144; }
    const int tilesX = C >> 5;
    wtrans_tile256(S, D, R, C, t % tilesX, t / tilesX, sc, tle);
  }
}

// ---- GEMM 128x128 tile, BK=32, 512 threads (8 waves, 4x2), 3-buf counted vmcnt --
template <int EPI>
__device__ __forceinline__ void gemm_body(
    _Float16* smem,                     // 3 bufs x (A 4096 + B 4096) f16 = 48 KB
    const _Float16* __restrict__ A, const _Float16* __restrict__ BT,
    int N, int K, int bm, int bn,
    _Float16* __restrict__ C16, _Float16* __restrict__ X16,
    const float* __restrict__ bias, const float* __restrict__ alpha_p,
    const float* __restrict__ gamma, const _Float16* __restrict__ resid16,
    float* __restrict__ outf)
{
  const int tid = threadIdx.x;                   // 0..511
  const int w = tid >> 6, l = tid & 63;
  const int g = l >> 4, r = l & 15;
  const int wm = w >> 1, wn = w & 1;             // 4 x 2 wave grid
  const int srow = tid >> 2;                     // 0..127
  const int skey = (tid >> 3) & 3;               // = (srow>>1)&3
  const int scol = ((tid & 3) ^ skey) << 3;      // pre-swizzled source f16 col

  const _Float16* gA = A + (size_t)(bm + srow) * K + scol;
  const _Float16* gB = BT + (size_t)(bn + srow) * K + scol;
  char* dA = (char*)smem + tid * 16;             // A region [0,8192) per buf
  char* dB = (char*)smem + 8192 + tid * 16;      // B region [8192,16384) per buf

  const int rk = (r >> 1) & 3;                   // read-side swizzle key
  const int gsw = (g ^ rk) << 3;                 // swizzled fragment col (f16)

  f32x4 acc[2][4] = {};
  const int KT = K >> 5;

  auto stage = [&](int buf) {
    gload_lds16(gA, dA + buf * 16384);
    gload_lds16(gB, dB + buf * 16384);
    gA += 32; gB += 32;
  };

  stage(0);
  stage(1);

  int cur = 0;
  for (int kt = 0; kt < KT; ++kt) {
    if (kt < KT - 1) asm volatile("s_waitcnt vmcnt(2) lgkmcnt(0)" ::: "memory");
    else             asm volatile("s_waitcnt vmcnt(0) lgkmcnt(0)" ::: "memory");
    __builtin_amdgcn_s_barrier();
    asm volatile("" ::: "memory");
    if (kt + 2 < KT) { int b2 = cur + 2; if (b2 >= 3) b2 -= 3; stage(b2); }
    const _Float16* Asc = smem + cur * 8192;
    const _Float16* Bsc = Asc + 4096;
    f16x8 af[2], bf[4];
#pragma unroll
    for (int m = 0; m < 2; ++m)
      af[m] = *(const f16x8*)(Asc + (wm * 32 + m * 16 + r) * 32 + gsw);
#pragma unroll
    for (int n = 0; n < 4; ++n)
      bf[n] = *(const f16x8*)(Bsc + (wn * 64 + n * 16 + r) * 32 + gsw);
    __builtin_amdgcn_s_setprio(1);
#pragma unroll
    for (int m = 0; m < 2; ++m)
#pragma unroll
      for (int n = 0; n < 4; ++n)
        acc[m][n] = mfma16(af[m], bf[n], acc[m][n]);
    __builtin_amdgcn_s_setprio(0);
    ++cur; if (cur == 3) cur = 0;
  }

  const int row0 = bm + wm * 32 + 4 * g;
  const int col0 = bn + wn * 64 + r;

  if constexpr (EPI == 5) {
    if (bn < 1024) {
#pragma unroll
      for (int m = 0; m < 2; ++m)
#pragma unroll
        for (int n = 0; n < 4; ++n)
#pragma unroll
          for (int rr = 0; rr < 4; ++rr)
            C16[(size_t)(row0 + m * 16 + rr) * 1024 + col0 + n * 16] =
                (_Float16)acc[m][n][rr];
    } else {
#pragma unroll
      for (int m = 0; m < 2; ++m) {
        const int row = row0 + m * 16;
        const int bq = row >> 10, nk = row & 1023;
#pragma unroll
        for (int n = 0; n < 4; ++n) {
          const int vcol = col0 + n * 16 - 1024;
          f16x4 t;
#pragma unroll
          for (int rr = 0; rr < 4; ++rr) t[rr] = (_Float16)acc[m][n][rr];
          *(f16x4*)(X16 + ((size_t)((bq << 4) + (vcol >> 6)) * 64 + (vcol & 63)) * 1024 + nk) = t;
        }
      }
    }
    return;
  }

#pragma unroll
  for (int m = 0; m < 2; ++m) {
#pragma unroll
    for (int n = 0; n < 4; ++n) {
#pragma unroll
      for (int rr = 0; rr < 4; ++rr) {
        const int row = row0 + m * 16 + rr;
        const int col = col0 + n * 16;
        const size_t idx = (size_t)row * N + col;
        float v = acc[m][n][rr];
        if constexpr (EPI == 0) {
          C16[idx] = (_Float16)v;
        } else if constexpr (EPI == 2) {
          float x = v + bias[col];
          X16[idx] = (_Float16)x;
          C16[idx] = (_Float16)(gamma[col] * tanhf(alpha_p[0] * x));
        } else if constexpr (EPI == 3) {
          float tt = v + bias[col];
          C16[idx] = (_Float16)(0.5f * tt * (1.0f + erff(tt * 0.7071067811865475f)));
        } else {
          outf[idx] = (float)resid16[idx] + v + bias[col];
        }
      }
    }
  }
}

template <int EPI>
__global__ __launch_bounds__(512, 6) void gemm_f16(
    const _Float16* __restrict__ A, const _Float16* __restrict__ BT,
    int N, int K, int nTnShift,
    _Float16* __restrict__ C16, _Float16* __restrict__ X16,
    const float* __restrict__ bias, const float* __restrict__ alpha_p,
    const float* __restrict__ gamma, const _Float16* __restrict__ resid16,
    float* __restrict__ outf)
{
  __shared__ __align__(16) _Float16 smem[24576];
  const int chunk = gridDim.x >> 3;
  const int bid = ((int)blockIdx.x & 7) * chunk + ((int)blockIdx.x >> 3);
  const int bm = (bid >> nTnShift) << 7;
  const int bn = (bid & ((1 << nTnShift) - 1)) << 7;
  gemm_body<EPI>(smem, A, BT, N, K, bm, bn,
                 C16, X16, bias, alpha_p, gamma, resid16, outf);
}

// fused Q-proj + KV-proj (K + transposed-V epilogue), one dispatch, XCD-swizzled
__global__ __launch_bounds__(512, 6) void gemm_qkv(
    const _Float16* __restrict__ Aq, const _Float16* __restrict__ Bq,
    _Float16* __restrict__ Cq,
    const _Float16* __restrict__ Ak, const _Float16* __restrict__ Bk,
    _Float16* __restrict__ K16, _Float16* __restrict__ VT)
{
  __shared__ __align__(16) _Float16 smem[24576];
  int bid = ((int)blockIdx.x & 7) * 96 + ((int)blockIdx.x >> 3);
  if (bid < 256) {
    gemm_body<0>(smem, Aq, Bq, 1024, 1024, (bid >> 3) << 7, (bid & 7) << 7,
                 Cq, nullptr, nullptr, nullptr, nullptr, nullptr, nullptr);
  } else {
    bid -= 256;
    gemm_body<5>(smem, Ak, Bk, 2048, 1024, (bid >> 4) << 7, (bid & 15) << 7,
                 K16, VT, nullptr, nullptr, nullptr, nullptr, nullptr);
  }
}

// ------- Flash attention: PURE, 512 blocks x 256 threads --------------------------
// 4 waves x 32 q-rows = 128 q-rows/block, shared K/V tiles.
// 4-buf LDS ring (64 KB), stage 2 tiles ahead, counted vmcnt(8), ONE barrier/iter.
// Row-sum l computed on the MFMA pipe: lacc = mfma32(ones, P) (no VALU adds,
// no final shuffle; denominator uses the same f16-rounded P as the numerator).
__global__ __launch_bounds__(256) void attn_kernel(
    const _Float16* __restrict__ Q, const _Float16* __restrict__ K16,
    const _Float16* __restrict__ VT, _Float16* __restrict__ O)
{
  __shared__ __align__(16) char smemc[65536];   // 4 bufs x (K 8KB | V 8KB)

  const int tid = threadIdx.x;

  const int bid = ((int)blockIdx.x & 7) * 64 + ((int)blockIdx.x >> 3);
  const int qb = bid & 7, hh = (bid >> 3) & 15, b = bid >> 7;
  const int w = tid >> 6, l = tid & 63;
  const int r = l & 31, h2 = l >> 5;
  const int q0 = qb * 128 + w * 32;

  f16x8 qf[4];
  {
    const _Float16* qp = Q + (size_t)(b * 1024 + q0 + r) * 1024 + hh * 64 + 8 * h2;
#pragma unroll
    for (int s = 0; s < 4; ++s) qf[s] = *(const f16x8*)(qp + s * 16);
  }

  f16x8 onef;
#pragma unroll
  for (int i = 0; i < 8; ++i) onef[i] = (_Float16)1.0f;

  f32x16 oacc0 = {}, oacc1 = {}, lacc = {};

  const int srow = tid >> 3, sslot = tid & 7;    // srow 0..31
  const int swz = (sslot ^ (srow & 7)) << 3;     // (row+32j)&7 == row&7
  const _Float16* kbase = K16 + (size_t)(b * 1024 + srow) * 1024 + hh * 64 + swz;
  const _Float16* vbase = VT + ((size_t)((b * 16 + hh) * 64) + srow) * 1024 + swz;
  char* kd0 = (char*)smemc + tid * 16;           // K region [0,8192) per buf
  char* vd0 = (char*)smemc + 8192 + tid * 16;    // V region [8192,16384) per buf

  auto stage = [&](int t) {
    const size_t kb = (size_t)(t << 6);
    const int buf = t & 3;
    char* kd = kd0 + buf * 16384;
    char* vd = vd0 + buf * 16384;
#pragma unroll
    for (int j = 0; j < 2; ++j)
      gload_lds16(kbase + (kb + 32 * j) * 1024, kd + j * 4096);
#pragma unroll
    for (int j = 0; j < 2; ++j)
      gload_lds16(vbase + (size_t)(32 * j) * 1024 + kb, vd + j * 4096);
  };

  stage(0);
  stage(1);

  const int rsw0 = r & 7;

  for (int kt = 0; kt < 16; ++kt) {
    if (kt + 2 < 16) stage(kt + 2);              // issued BEFORE the wait
    if (kt < 14)       asm volatile("s_waitcnt vmcnt(8)" ::: "memory");
    else if (kt == 14) asm volatile("s_waitcnt vmcnt(4)" ::: "memory");
    else               asm volatile("s_waitcnt vmcnt(0)" ::: "memory");
    __builtin_amdgcn_s_barrier();
    asm volatile("" ::: "memory");

    const _Float16* Kc = (const _Float16*)(smemc + (kt & 3) * 16384);
    const _Float16* Vc = Kc + 4096;

    f32x16 s0 = {}, s1 = {};
    __builtin_amdgcn_s_setprio(1);
#pragma unroll
    for (int s = 0; s < 4; ++s) {
      const int cch = 2 * s + h2;
      f16x8 a0 = *(const f16x8*)(Kc + r * 64 + ((cch ^ rsw0) << 3));
      f16x8 a1 = *(const f16x8*)(Kc + (32 + r) * 64 + ((cch ^ rsw0) << 3));
      s0 = mfma32(a0, qf[s], s0);
      s1 = mfma32(a1, qf[s], s1);
    }
    __builtin_amdgcn_s_setprio(0);

    // p = 2^s (f32), pack to f16; l comes from an extra MFMA below
#pragma unroll
    for (int i = 0; i < 16; ++i) s0[i] = __builtin_amdgcn_exp2f(s0[i]);
#pragma unroll
    for (int i = 0; i < 16; ++i) s1[i] = __builtin_amdgcn_exp2f(s1[i]);

    unsigned own[16];
#pragma unroll
    for (int u = 0; u < 8; ++u) {
      const int tb = (u & 3) * 4;
      if (u < 4) {
        own[2 * u]     = pkrtz(s0[tb], s0[tb + 1]);
        own[2 * u + 1] = pkrtz(s0[tb + 2], s0[tb + 3]);
      } else {
        own[2 * u]     = pkrtz(s1[tb], s1[tb + 1]);
        own[2 * u + 1] = pkrtz(s1[tb + 2], s1[tb + 3]);
      }
    }
    f16x8 pf[4];
#pragma unroll
    for (int s = 0; s < 4; ++s) {
      auto r0 = __builtin_amdgcn_permlane32_swap(own[4 * s], own[4 * s + 2], false, false);
      auto r1 = __builtin_amdgcn_permlane32_swap(own[4 * s + 1], own[4 * s + 3], false, false);
      union { unsigned u[4]; f16x8 v; } fu;
      fu.u[0] = r0[0]; fu.u[1] = r1[0]; fu.u[2] = r0[1]; fu.u[3] = r1[1];
      pf[s] = fu.v;
    }

    __builtin_amdgcn_s_setprio(1);
#pragma unroll
    for (int s = 0; s < 4; ++s) {
      const int cch = 2 * s + h2;
      f16x8 va = *(const f16x8*)(Vc + r * 64 + ((cch ^ rsw0) << 3));
      f16x8 vb = *(const f16x8*)(Vc + (32 + r) * 64 + ((cch ^ rsw0) << 3));
      oacc0 = mfma32(va, pf[s], oacc0);
      oacc1 = mfma32(vb, pf[s], oacc1);
      lacc  = mfma32(onef, pf[s], lacc);
    }
    __builtin_amdgcn_s_setprio(0);
    asm volatile("" ::: "memory");   // keep next iter's stage below this point
  }

  const float inv = 1.0f / lacc[0];
  _Float16* op = O + (size_t)(b * 1024 + q0 + r) * 1024 + hh * 64 + 4 * h2;
#pragma unroll
  for (int u = 0; u < 4; ++u) {
    f16x4 t0, t1;
#pragma unroll
    for (int v = 0; v < 4; ++v) {
      t0[v] = (_Float16)(oacc0[4 * u + v] * inv);
      t1[v] = (_Float16)(oacc1[4 * u + v] * inv);
    }
    *(f16x4*)(op + 8 * u) = t0;
    *(f16x4*)(op + 32 + 8 * u) = t1;
  }
}

extern "C" void kernel_launch(void* const* d_in, const int* in_sizes, int n_in,
                              void* d_out, int out_size, void* d_ws, size_t ws_size,
                              hipStream_t stream)
{
  const float* xk      = (const float*)d_in[0];
  const float* xq      = (const float*)d_in[1];
  const float* alpha_q = (const float*)d_in[2];
  const float* gamma_q = (const float*)d_in[3];
  const float* alpha_k = (const float*)d_in[4];
  const float* gamma_k = (const float*)d_in[5];
  const float* Wq      = (const float*)d_in[6];
  const float* Wkv     = (const float*)d_in[7];
  const float* Wproj   = (const float*)d_in[8];
  const float* bproj   = (const float*)d_in[9];
  const float* alpha2  = (const float*)d_in[10];
  const float* gamma2  = (const float*)d_in[11];
  const float* W1      = (const float*)d_in[12];
  const float* b1      = (const float*)d_in[13];
  const float* W2      = (const float*)d_in[14];
  const float* b2      = (const float*)d_in[15];

  char* p = (char*)d_ws;
  _Float16* xqn    = (_Float16*)p; p += 8388608;
  _Float16* xkn    = (_Float16*)p; p += 8388608;
  _Float16* WqT    = (_Float16*)p; p += 2097152;
  _Float16* WkvT   = (_Float16*)p; p += 4194304;
  _Float16* WprojT = (_Float16*)p; p += 2097152;
  _Float16* W1T    = (_Float16*)p; p += 4194304;
  _Float16* W2T    = (_Float16*)p; p += 4194304;
  _Float16* q16    = (_Float16*)p; p += 8388608;
  _Float16* vt16   = (_Float16*)p; p += 8388608;
  _Float16* k16    = (_Float16*)p; p += 8388608;
  _Float16* h16    = (_Float16*)p; p += 16777216;
  _Float16* o16    = (_Float16*)p; p += 8388608;
  // aliases (lifetimes disjoint):
  _Float16* x16  = q16;           // q16 dead after attn; x written at proj
  _Float16* g16  = xqn;           // xqn dead after gemm_qkv
  float*    outf = (float*)d_out;

  prep_kernel<<<16384, 256, 0, stream>>>(xq, xk, alpha_q, gamma_q, alpha_k, gamma_k,
      xqn, xkn, Wq, Wkv, WqT, WkvT, Wproj, W1, W2, WprojT, W1T, W2T);
  gemm_qkv<<<768, 512, 0, stream>>>(xqn, WqT, q16, xkn, WkvT, k16, vt16);
  attn_kernel<<<512, 256, 0, stream>>>(q16, k16, vt16, o16);
  gemm_f16<2><<<256, 512, 0, stream>>>(o16, WprojT, 1024, 1024, 3,
      g16, x16, bproj, alpha2, gamma2, nullptr, nullptr);
  gemm_f16<3><<<512, 512, 0, stream>>>(g16, W1T, 2048, 1024, 4,
      h16, nullptr, b1, nullptr, nullptr, nullptr, nullptr);
  gemm_f16<4><<<256, 512, 0, stream>>>(h16, W2T, 1024, 2048, 3,
      nullptr, nullptr, b2, nullptr, nullptr, x16, outf);
}